// Round 11
// baseline (156.895 us; speedup 1.0000x reference)
//
#include <hip/hip_runtime.h>
#include <hip/hip_bf16.h>

// Problem constants
#define BB 2
#define SS 2048
#define DD 128
#define HH 8
#define HDIM 16
#define DF 512
#define SPK 36        // attn P stride (shorts); 72B rows
#define HS 520        // ffn LDS h stride (shorts; %8==0 for b128 alignment)
#define LNS 136       // LN LDS stride (shorts; %8==0 for b128 alignment)

typedef float floatx4 __attribute__((ext_vector_type(4)));
typedef float floatx16 __attribute__((ext_vector_type(16)));
typedef short frag8 __attribute__((ext_vector_type(8)));

__device__ __forceinline__ short f2bf(float x) {
  union { __hip_bfloat16 h; short s; } u;
  u.h = __float2bfloat16(x);
  return u.s;
}
// packed pair convert: v_cvt_pk_bf16_f32
__device__ __forceinline__ unsigned int pkbf(float a, float b) {
  float2 f; f.x = a; f.y = b;
  union { __hip_bfloat162 h2; unsigned int u; } u;
  u.h2 = __float22bfloat162_rn(f);
  return u.u;
}
__device__ __forceinline__ frag8 cvt8(const float4 a, const float4 b) {
  union { frag8 f; unsigned int u[4]; } x;
  x.u[0] = pkbf(a.x, a.y);
  x.u[1] = pkbf(a.z, a.w);
  x.u[2] = pkbf(b.x, b.y);
  x.u[3] = pkbf(b.z, b.w);
  return x.f;
}

// ---------------- weight prep: WT[n][k] bf16, scale folded ----------------
struct WSrc { const float* p[10]; };
// order: self_wq,self_wk,self_wv,cross_wq,cross_wk,cross_wv,w1,w2,w3,w4
__global__ __launch_bounds__(256) void wprep_kernel(WSrc w, short* __restrict__ dst) {
  const int wi = blockIdx.y;
  const int kshift = (wi == 9) ? 9 : 7;          // K: 512 for w4, else 128
  const int N = (wi == 8) ? 512 : 128;           // w3 has N=512
  const int total = N << kshift;
  const int offs[10] = {0, 16384, 32768, 49152, 65536, 81920, 98304, 114688, 131072, 196608};
  // fold 1/sqrt(HD) AND log2(e) into Wq: scores land in log2 domain -> bare v_exp
  const float sc = (wi == 0 || wi == 3) ? 0.25f * 1.4426950408889634f : 1.0f;
  const float* src = w.p[wi];
  short* d = dst + offs[wi];
  const int K = 1 << kshift;
  for (int idx = blockIdx.x * 256 + threadIdx.x; idx < total; idx += gridDim.x * 256) {
    const int n = idx >> kshift, k = idx & (K - 1);
    d[idx] = f2bf(src[k * N + n] * sc);
  }
}

// ---------------- fused 6-way QKV projection (MFMA), 2-wave blocks ----------
// grid (M/16, 6), block 128 (2 waves). blockIdx.y: 0..2 self QKV (A=x_tgt),
// 3 cross Q (A=enc_out, quirk), 4..5 cross K/V (A=x_tgt).
// Wave wv computes output cols [wv*64, wv*64+64); shared sC epilogue.
__global__ __launch_bounds__(128) void qkv_kernel(const float* __restrict__ x_tgt,
                                                  const float* __restrict__ enc_out,
                                                  const short* __restrict__ wt,
                                                  short* __restrict__ Qs, short* __restrict__ Ks,
                                                  short* __restrict__ Vts,
                                                  short* __restrict__ Qc, short* __restrict__ Kc,
                                                  short* __restrict__ Vtc) {
  const int t = threadIdx.x, wv = t >> 6, lane = t & 63;
  const int quad = lane >> 4, l16 = lane & 15;
  const int mbase = blockIdx.x * 16;
  const int which = blockIdx.y;
  const int kind = which % 3;  // 0=Q,1=K,2=Vt
  const float* A = (which == 3) ? enc_out : x_tgt;
  const short* W = wt + which * 16384;
  short* Qb = (which < 3) ? Qs : Qc;
  short* Kb = (which < 3) ? Ks : Kc;
  short* Vtb = (which < 3) ? Vts : Vtc;

  __shared__ short sC[16 * 130];  // [m-local][n] bf16, stride 130

  floatx4 acc[4];
#pragma unroll
  for (int ci = 0; ci < 4; ci++) acc[ci] = (floatx4){0.f, 0.f, 0.f, 0.f};

#pragma unroll
  for (int ks = 0; ks < 4; ks++) {
    const float4* ar = (const float4*)&A[(size_t)(mbase + l16) * DD + ks * 32 + quad * 8];
    const frag8 af = cvt8(ar[0], ar[1]);
#pragma unroll
    for (int ci = 0; ci < 4; ci++) {
      const int ct = wv * 4 + ci;
      const frag8 bf = *(const frag8*)&W[(ct * 16 + l16) * DD + ks * 32 + quad * 8];
      acc[ci] = __builtin_amdgcn_mfma_f32_16x16x32_bf16(af, bf, acc[ci], 0, 0, 0);
    }
  }

#pragma unroll
  for (int ci = 0; ci < 4; ci++) {
#pragma unroll
    for (int r = 0; r < 4; r++) {
      sC[(quad * 4 + r) * 130 + (wv * 4 + ci) * 16 + l16] = f2bf(acc[ci][r]);
    }
  }
  __syncthreads();

  const int b = mbase >> 11;
  const int sbase = mbase & 2047;
  if (kind <= 1) {
    short* Dst = (kind == 0) ? Qb : Kb;
    const int s = lane >> 2, c4 = lane & 3;
#pragma unroll
    for (int hh = 0; hh < 4; hh++) {
      const int h = wv * 4 + hh;
      short4 v;  // split quirk: n = dci*8 + h
      v.x = sC[s * 130 + (c4 * 4 + 0) * 8 + h];
      v.y = sC[s * 130 + (c4 * 4 + 1) * 8 + h];
      v.z = sC[s * 130 + (c4 * 4 + 2) * 8 + h];
      v.w = sC[s * 130 + (c4 * 4 + 3) * 8 + h];
      const int bh = b * HH + h;
      *(short4*)&Dst[((size_t)bh * SS + sbase + s) * HDIM + c4 * 4] = v;
    }
  } else {
    const int dci = lane >> 2, c4 = lane & 3;
#pragma unroll
    for (int hh = 0; hh < 4; hh++) {
      const int h = wv * 4 + hh;
      short4 v;
      v.x = sC[(c4 * 4 + 0) * 130 + dci * 8 + h];
      v.y = sC[(c4 * 4 + 1) * 130 + dci * 8 + h];
      v.z = sC[(c4 * 4 + 2) * 130 + dci * 8 + h];
      v.w = sC[(c4 * 4 + 3) * 130 + dci * 8 + h];
      const int bh = b * HH + h;
      *(short4*)&Vtb[((size_t)bh * HDIM + dci) * SS + sbase + c4 * 4] = v;
    }
  }
}

// ---------------- MFMA flash attention: 32x32x16 QK, split-K 4-wave blocks ----
// grid (SS/32, BB*HH, 2), block 256 = 4 waves; wave w owns keys [w*512, w*512+512).
// Q pre-scaled by 1/sqrt(HD)*log2(e): numerators via bare v_exp_f32.
// sP is double-buffered on iteration parity (breaks the write->read WAR chain);
// the partial-combine arrays alias the sP buffers post-loop (LDS stays 18.4 KB).
__global__ __launch_bounds__(256) void attn_mfma_kernel(
    const short* __restrict__ Qa, const short* __restrict__ Ka,
    const short* __restrict__ Vta, short* __restrict__ AMa,
    const short* __restrict__ Qc, const short* __restrict__ Kc,
    const short* __restrict__ Vtc, short* __restrict__ AMc) {
  const int t = threadIdx.x, wid = t >> 6, lane = t & 63;
  const int l32 = lane & 31, half = lane >> 5;   // 32-wide frag coords
  const int quad = (lane >> 4) & 3, l16 = lane & 15;
  const int bh = blockIdx.y;
  const int qbase = blockIdx.x * 32;
  const int inst = blockIdx.z;
  const short* Q = inst ? Qc : Qa;
  const short* K = inst ? Kc : Ka;
  const short* Vt = inst ? Vtc : Vta;
  short* AM = inst ? AMc : AMa;
  const size_t headoff = (size_t)bh * SS;

  // [parity][wave][q][key(32)] bf16; per-wave slice = 2304 B.
  // Post-loop aliases: pnum(wave w) = sP[0][w] (16*33 fp32 = 2112 B fits),
  //                    pl(wave w)   = sP[1][w] (32 fp32).
  __shared__ short sP[2][4][32 * SPK];

  // Q B-frag (32x32x16): n=q=l32, k=half*8+j
  const frag8 qf = *(const frag8*)&Q[(headoff + qbase + l32) * HDIM + half * 8];

  frag8 onef;
#pragma unroll
  for (int i = 0; i < 8; i++) onef[i] = (short)0x3f80;  // bf16 1.0

  floatx4 acc_o[2], acc_l[2];
  acc_o[0] = (floatx4){0.f, 0.f, 0.f, 0.f}; acc_o[1] = acc_o[0];
  acc_l[0] = acc_o[0]; acc_l[1] = acc_o[0];

  const int keyw = wid * 512;
#pragma unroll 2
  for (int it = 0; it < 16; it++) {
    const int kb = keyw + it * 32;
    short* sPw = &sP[it & 1][wid][0];
    // K A-frag: m=key=l32, k=half*8+j — branchless b128
    const frag8 kf = *(const frag8*)&K[(headoff + kb + l32) * HDIM + half * 8];
    const floatx16 z16 = {0.f};
    // C[m=key][n=q]: col=lane&31=q, row=key=(reg&3)+8*(reg>>2)+4*half
    const floatx16 sc = __builtin_amdgcn_mfma_f32_32x32x16_bf16(kf, qf, z16, 0, 0, 0);
    // bare v_exp + packed cvt: reg group g = keys 8g+4*half+0..3 at fixed q=l32
#pragma unroll
    for (int g = 0; g < 4; g++) {
      const float e0 = __builtin_amdgcn_exp2f(sc[4 * g + 0]);
      const float e1 = __builtin_amdgcn_exp2f(sc[4 * g + 1]);
      const float e2 = __builtin_amdgcn_exp2f(sc[4 * g + 2]);
      const float e3 = __builtin_amdgcn_exp2f(sc[4 * g + 3]);
      uint2 pk;
      pk.x = pkbf(e0, e1);
      pk.y = pkbf(e2, e3);
      *(uint2*)&sPw[l32 * SPK + g * 8 + half * 4] = pk;
    }
    // PV (operand-swapped, 16x16x32): C[d][q'] += Vt(16d x 32k) @ P^T(32k x 16q')
#pragma unroll
    for (int qh = 0; qh < 2; qh++) {
      const frag8 pf = *(const frag8*)&sPw[(qh * 16 + l16) * SPK + quad * 8];
      const frag8 vf = *(const frag8*)&Vt[((size_t)bh * HDIM + l16) * SS + kb + quad * 8];
      acc_o[qh] = __builtin_amdgcn_mfma_f32_16x16x32_bf16(vf, pf, acc_o[qh], 0, 0, 0);
      acc_l[qh] = __builtin_amdgcn_mfma_f32_16x16x32_bf16(onef, pf, acc_l[qh], 0, 0, 0);
    }
  }

  // stage per-wave partials into the aliased sP regions (per-wave slices; DS ops
  // within a wave execute in order, so the last pf reads complete first).
  {
    float* pn = (float*)&sP[0][wid][0];
    float* plw = (float*)&sP[1][wid][0];
#pragma unroll
    for (int qh = 0; qh < 2; qh++) {
#pragma unroll
      for (int r = 0; r < 4; r++) {
        pn[(quad * 4 + r) * 33 + qh * 16 + l16] = acc_o[qh][r];
      }
      if (quad == 0) plw[qh * 16 + l16] = acc_l[qh][0];  // rows replicated
    }
  }
  __syncthreads();

  {
    const int b = bh >> 3, h = bh & 7;
#pragma unroll
    for (int idx = t; idx < 512; idx += 256) {
      const int q16 = idx & 31, d = idx >> 5;
      float num = 0.f, l = 0.f;
#pragma unroll
      for (int w = 0; w < 4; w++) {
        num += ((const float*)&sP[0][w][0])[d * 33 + q16];
        l += ((const float*)&sP[1][w][0])[q16];
      }
      AM[((size_t)b * SS + qbase + q16) * DD + d * 8 + h] = f2bf(num / l);
    }
  }
}

// ---------------- fused tail: residual GEMMs + norm + FFN (8-wave blocks) ----
// out = relu(LN@W3+b3)@W4 + b4 + R2, where R2 = AMs@w1 + AMc@w2 + b1+b2 + x_tgt
// and LN = (R2-mean)/var. R2/LN never hit global; FFN2 residual = in-register v.
// grid M/16, block 512 = 8 waves; wave w owns cols [w*16, w*16+16) in phases A/C
// (so the phase-A R2 registers ARE the phase-C residual) and h cols
// [w*64, w*64+64) in phase B.
__global__ __launch_bounds__(512) void tail_kernel(
    const short* __restrict__ AMs, const short* __restrict__ AMc,
    const short* __restrict__ W1, const short* __restrict__ W2,
    const float* __restrict__ b1, const float* __restrict__ b2,
    const float* __restrict__ x_tgt,
    const short* __restrict__ W3, const float* __restrict__ b3,
    const short* __restrict__ W4, const float* __restrict__ b4,
    float* __restrict__ Out) {
  const int t = threadIdx.x, w = t >> 6, lane = t & 63;
  const int quad = lane >> 4, l16 = lane & 15;
  const int mbase = blockIdx.x * 16;
  const int nA = w * 16 + l16;  // this wave's column in phases A and C

  __shared__ float sumS[8][16];
  __shared__ float sumQ[8][16];
  __shared__ short sLN[16 * LNS];
  __shared__ short hs[16 * HS];

  // ---- phase A: R2 col-slice = AMs@W1 + AMc@W2 + b1 + b2 + x_tgt ----
  floatx4 acc2 = (floatx4){0.f, 0.f, 0.f, 0.f};
#pragma unroll
  for (int ks = 0; ks < 4; ks++) {
    const frag8 afS = *(const frag8*)&AMs[(size_t)(mbase + l16) * DD + ks * 32 + quad * 8];
    const frag8 afC = *(const frag8*)&AMc[(size_t)(mbase + l16) * DD + ks * 32 + quad * 8];
    const frag8 bf1 = *(const frag8*)&W1[nA * DD + ks * 32 + quad * 8];
    const frag8 bf2 = *(const frag8*)&W2[nA * DD + ks * 32 + quad * 8];
    acc2 = __builtin_amdgcn_mfma_f32_16x16x32_bf16(afS, bf1, acc2, 0, 0, 0);
    acc2 = __builtin_amdgcn_mfma_f32_16x16x32_bf16(afC, bf2, acc2, 0, 0, 0);
  }

  float v[4];  // R2 values; survive to phase C as the residual
  {
    const float bn = b1[nA] + b2[nA];
#pragma unroll
    for (int r = 0; r < 4; r++) {
      const int m = mbase + quad * 4 + r;
      v[r] = acc2[r] + bn + x_tgt[(size_t)m * DD + nA];
    }
  }

  // ---- norm: per-wave 16-col partial sums, combined across 8 waves ----
#pragma unroll
  for (int r = 0; r < 4; r++) {
    float s = v[r];
    float sq = v[r] * v[r];
#pragma unroll
    for (int mk = 1; mk < 16; mk <<= 1) {
      s += __shfl_xor(s, mk, 64);
      sq += __shfl_xor(sq, mk, 64);
    }
    if (l16 == 0) {
      sumS[w][quad * 4 + r] = s;
      sumQ[w][quad * 4 + r] = sq;
    }
  }
  __syncthreads();

#pragma unroll
  for (int r = 0; r < 4; r++) {
    const int row = quad * 4 + r;
    float S = 0.f, Qs_ = 0.f;
#pragma unroll
    for (int ww = 0; ww < 8; ww++) { S += sumS[ww][row]; Qs_ += sumQ[ww][row]; }
    const float mean = S * (1.0f / 128.0f);
    const float cs = Qs_ - S * mean;        // sum of squared deviations
    const float ivar = 127.0f / cs;         // 1/var, var = cs/127 (faithful quirk)
    sLN[row * LNS + nA] = f2bf((v[r] - mean) * ivar);
  }
  __syncthreads();

  // ---- phase B: h = relu(LN @ W3 + b3), wave w -> h cols [w*64,(w+1)*64) ----
  {
    floatx4 acc[4];
#pragma unroll
    for (int ci = 0; ci < 4; ci++) acc[ci] = (floatx4){0.f, 0.f, 0.f, 0.f};
    const int nblk = w * 64;
#pragma unroll
    for (int ks = 0; ks < 4; ks++) {
      const frag8 af = *(const frag8*)&sLN[l16 * LNS + ks * 32 + quad * 8];
#pragma unroll
      for (int ci = 0; ci < 4; ci++) {
        const frag8 bf = *(const frag8*)&W3[(size_t)(nblk + ci * 16 + l16) * DD + ks * 32 + quad * 8];
        acc[ci] = __builtin_amdgcn_mfma_f32_16x16x32_bf16(af, bf, acc[ci], 0, 0, 0);
      }
    }
#pragma unroll
    for (int ci = 0; ci < 4; ci++) {
      const int n = nblk + ci * 16 + l16;
      const float bn = b3[n];
#pragma unroll
      for (int r = 0; r < 4; r++) {
        hs[(quad * 4 + r) * HS + n] = f2bf(fmaxf(acc[ci][r] + bn, 0.f));
      }
    }
  }
  __syncthreads();

  // ---- phase C: out = h @ W4 + b4 + v (in-register residual) ----
  {
    floatx4 acc = (floatx4){0.f, 0.f, 0.f, 0.f};
#pragma unroll 4
    for (int ks = 0; ks < 16; ks++) {
      const frag8 af = *(const frag8*)&hs[l16 * HS + ks * 32 + quad * 8];
      const frag8 bf = *(const frag8*)&W4[(size_t)nA * DF + ks * 32 + quad * 8];
      acc = __builtin_amdgcn_mfma_f32_16x16x32_bf16(af, bf, acc, 0, 0, 0);
    }
    const float bn = b4[nA];
#pragma unroll
    for (int r = 0; r < 4; r++) {
      const int m = mbase + quad * 4 + r;
      Out[(size_t)m * DD + nA] = acc[r] + bn + v[r];
    }
  }
}

extern "C" void kernel_launch(void* const* d_in, const int* in_sizes, int n_in,
                              void* d_out, int out_size, void* d_ws, size_t ws_size,
                              hipStream_t stream) {
  (void)in_sizes; (void)n_in; (void)out_size; (void)ws_size;
  const float* x_tgt   = (const float*)d_in[0];
  const float* enc_out = (const float*)d_in[1];
  const float* b1 = (const float*)d_in[9];
  const float* b2 = (const float*)d_in[11];
  const float* b3 = (const float*)d_in[13];
  const float* b4 = (const float*)d_in[15];

  WSrc wsrc;
  wsrc.p[0] = (const float*)d_in[2];   // self_wq
  wsrc.p[1] = (const float*)d_in[3];   // self_wk
  wsrc.p[2] = (const float*)d_in[4];   // self_wv
  wsrc.p[3] = (const float*)d_in[5];   // cross_wq
  wsrc.p[4] = (const float*)d_in[6];   // cross_wk
  wsrc.p[5] = (const float*)d_in[7];   // cross_wv
  wsrc.p[6] = (const float*)d_in[8];   // w1
  wsrc.p[7] = (const float*)d_in[10];  // w2
  wsrc.p[8] = (const float*)d_in[12];  // w3
  wsrc.p[9] = (const float*)d_in[14];  // w4

  // workspace layout (float-slot offsets; bf16 buffers use 2 elems per slot)
  float* ws = (float*)d_ws;
  short* wt   = (short*)(ws + 0);          // 262144 bf16 (512 KB)
  short* Qs   = (short*)(ws + 131072);     // each QKV buf: 524288 bf16
  short* Ks   = (short*)(ws + 393216);
  short* Vts  = (short*)(ws + 655360);
  short* AMs  = (short*)(ws + 917504);
  short* Qc   = (short*)(ws + 1179648);
  short* Kc   = (short*)(ws + 1441792);
  short* Vtc  = (short*)(ws + 1703936);
  short* AMc  = (short*)(ws + 1966080);

  const int M = BB * SS;  // 4096
  const int MT = M / 16;  // 256 row-tiles

  wprep_kernel<<<dim3(64, 10), 256, 0, stream>>>(wsrc, wt);

  // all 6 projections in one launch (cross-Q reads enc_out — faithful quirk)
  qkv_kernel<<<dim3(MT, 6), 128, 0, stream>>>(x_tgt, enc_out, wt, Qs, Ks, Vts, Qc, Kc, Vtc);

  // both attentions in one launch; 32-query waves, split-K 4-wave blocks
  attn_mfma_kernel<<<dim3(SS / 32, BB * HH, 2), 256, 0, stream>>>(
      Qs, Ks, Vts, AMs, Qc, Kc, Vtc, AMc);

  // fused tail: residual GEMMs + norm + FFN (R2/LN never hit global)
  tail_kernel<<<MT, 512, 0, stream>>>(AMs, AMc, wt + 98304, wt + 114688,
                                      b1, b2, x_tgt, wt + 131072, b3,
                                      wt + 196608, b4, (float*)d_out);
}

// Round 12
// 155.496 us; speedup vs baseline: 1.0090x; 1.0090x over previous
//
#include <hip/hip_runtime.h>
#include <hip/hip_bf16.h>

// Problem constants
#define BB 2
#define SS 2048
#define DD 128
#define HH 8
#define HDIM 16
#define DF 512
#define HS 520        // ffn LDS h stride (shorts; %8==0 for b128 alignment)
#define LNS 136       // LN LDS stride (shorts; %8==0 for b128 alignment)

typedef float floatx4 __attribute__((ext_vector_type(4)));
typedef float floatx16 __attribute__((ext_vector_type(16)));
typedef short frag8 __attribute__((ext_vector_type(8)));

__device__ __forceinline__ short f2bf(float x) {
  union { __hip_bfloat16 h; short s; } u;
  u.h = __float2bfloat16(x);
  return u.s;
}
// packed pair convert: v_cvt_pk_bf16_f32
__device__ __forceinline__ unsigned int pkbf(float a, float b) {
  float2 f; f.x = a; f.y = b;
  union { __hip_bfloat162 h2; unsigned int u; } u;
  u.h2 = __float22bfloat162_rn(f);
  return u.u;
}
__device__ __forceinline__ frag8 cvt8(const float4 a, const float4 b) {
  union { frag8 f; unsigned int u[4]; } x;
  x.u[0] = pkbf(a.x, a.y);
  x.u[1] = pkbf(a.z, a.w);
  x.u[2] = pkbf(b.x, b.y);
  x.u[3] = pkbf(b.z, b.w);
  return x.f;
}

// ---------------- weight prep: WT[n][k] bf16, scale folded ----------------
struct WSrc { const float* p[10]; };
// order: self_wq,self_wk,self_wv,cross_wq,cross_wk,cross_wv,w1,w2,w3,w4
// slab wi==10: write the ones-row (row 16) of both 32-row Vt buffers.
__global__ __launch_bounds__(256) void wprep_kernel(WSrc w, short* __restrict__ dst,
                                                    short* __restrict__ Vts,
                                                    short* __restrict__ Vtc) {
  const int wi = blockIdx.y;
  if (wi == 10) {
    const int total = 2 * BB * HH * SS;  // 65536
    for (int idx = blockIdx.x * 256 + threadIdx.x; idx < total; idx += gridDim.x * 256) {
      const int inst2 = idx >> 15;
      const int rest = idx & 32767;
      const int bh = rest >> 11, s = rest & 2047;
      short* vt = inst2 ? Vtc : Vts;
      vt[((size_t)bh * 32 + 16) * SS + s] = (short)0x3f80;  // bf16 1.0
    }
    return;
  }
  const int kshift = (wi == 9) ? 9 : 7;          // K: 512 for w4, else 128
  const int N = (wi == 8) ? 512 : 128;           // w3 has N=512
  const int total = N << kshift;
  const int offs[10] = {0, 16384, 32768, 49152, 65536, 81920, 98304, 114688, 131072, 196608};
  // fold 1/sqrt(HD) AND log2(e) into Wq: scores land in log2 domain -> bare v_exp
  const float sc = (wi == 0 || wi == 3) ? 0.25f * 1.4426950408889634f : 1.0f;
  const float* src = w.p[wi];
  short* d = dst + offs[wi];
  const int K = 1 << kshift;
  for (int idx = blockIdx.x * 256 + threadIdx.x; idx < total; idx += gridDim.x * 256) {
    const int n = idx >> kshift, k = idx & (K - 1);
    d[idx] = f2bf(src[k * N + n] * sc);
  }
}

// ---------------- fused 6-way QKV projection (MFMA), 2-wave blocks ----------
// grid (M/16, 6), block 128 (2 waves). blockIdx.y: 0..2 self QKV (A=x_tgt),
// 3 cross Q (A=enc_out, quirk), 4..5 cross K/V (A=x_tgt).
// Vt buffers are 32 rows/head (rows 0-15 = dims; row 16 = ones via wprep).
__global__ __launch_bounds__(128) void qkv_kernel(const float* __restrict__ x_tgt,
                                                  const float* __restrict__ enc_out,
                                                  const short* __restrict__ wt,
                                                  short* __restrict__ Qs, short* __restrict__ Ks,
                                                  short* __restrict__ Vts,
                                                  short* __restrict__ Qc, short* __restrict__ Kc,
                                                  short* __restrict__ Vtc) {
  const int t = threadIdx.x, wv = t >> 6, lane = t & 63;
  const int quad = lane >> 4, l16 = lane & 15;
  const int mbase = blockIdx.x * 16;
  const int which = blockIdx.y;
  const int kind = which % 3;  // 0=Q,1=K,2=Vt
  const float* A = (which == 3) ? enc_out : x_tgt;
  const short* W = wt + which * 16384;
  short* Qb = (which < 3) ? Qs : Qc;
  short* Kb = (which < 3) ? Ks : Kc;
  short* Vtb = (which < 3) ? Vts : Vtc;

  __shared__ short sC[16 * 130];  // [m-local][n] bf16, stride 130

  floatx4 acc[4];
#pragma unroll
  for (int ci = 0; ci < 4; ci++) acc[ci] = (floatx4){0.f, 0.f, 0.f, 0.f};

#pragma unroll
  for (int ks = 0; ks < 4; ks++) {
    const float4* ar = (const float4*)&A[(size_t)(mbase + l16) * DD + ks * 32 + quad * 8];
    const frag8 af = cvt8(ar[0], ar[1]);
#pragma unroll
    for (int ci = 0; ci < 4; ci++) {
      const int ct = wv * 4 + ci;
      const frag8 bf = *(const frag8*)&W[(ct * 16 + l16) * DD + ks * 32 + quad * 8];
      acc[ci] = __builtin_amdgcn_mfma_f32_16x16x32_bf16(af, bf, acc[ci], 0, 0, 0);
    }
  }

#pragma unroll
  for (int ci = 0; ci < 4; ci++) {
#pragma unroll
    for (int r = 0; r < 4; r++) {
      sC[(quad * 4 + r) * 130 + (wv * 4 + ci) * 16 + l16] = f2bf(acc[ci][r]);
    }
  }
  __syncthreads();

  const int b = mbase >> 11;
  const int sbase = mbase & 2047;
  if (kind <= 1) {
    short* Dst = (kind == 0) ? Qb : Kb;
    const int s = lane >> 2, c4 = lane & 3;
#pragma unroll
    for (int hh = 0; hh < 4; hh++) {
      const int h = wv * 4 + hh;
      short4 v;  // split quirk: n = dci*8 + h
      v.x = sC[s * 130 + (c4 * 4 + 0) * 8 + h];
      v.y = sC[s * 130 + (c4 * 4 + 1) * 8 + h];
      v.z = sC[s * 130 + (c4 * 4 + 2) * 8 + h];
      v.w = sC[s * 130 + (c4 * 4 + 3) * 8 + h];
      const int bh = b * HH + h;
      *(short4*)&Dst[((size_t)bh * SS + sbase + s) * HDIM + c4 * 4] = v;
    }
  } else {
    const int dci = lane >> 2, c4 = lane & 3;
#pragma unroll
    for (int hh = 0; hh < 4; hh++) {
      const int h = wv * 4 + hh;
      short4 v;
      v.x = sC[(c4 * 4 + 0) * 130 + dci * 8 + h];
      v.y = sC[(c4 * 4 + 1) * 130 + dci * 8 + h];
      v.z = sC[(c4 * 4 + 2) * 130 + dci * 8 + h];
      v.w = sC[(c4 * 4 + 3) * 130 + dci * 8 + h];
      const int bh = b * HH + h;
      *(short4*)&Vtb[((size_t)bh * 32 + dci) * SS + sbase + c4 * 4] = v;
    }
  }
}

// ---------------- MFMA flash attention: LDS-free hot loop ----------------
// grid (SS/32, BB*HH, 2), block 256 = 4 waves; wave w owns keys [w*512, w*512+512).
// QK (32x32x16): C[key][q] with q=lane. P stays in REGISTERS: the PV A-fragment
// (m=q, k=key) is reached from the C-layout by a single half<->half key swap
// (__shfl_xor 32) + selects. PV (32x32x16): B = Vt32[n][key] where n=0..15 are
// V dims and n==16 is the ones-row -> C[q][16] = sum(P) = softmax denominator,
// free. No LDS in the loop; only the split-K combine uses LDS.
__global__ __launch_bounds__(256) void attn_mfma_kernel(
    const short* __restrict__ Qa, const short* __restrict__ Ka,
    const short* __restrict__ Vta, short* __restrict__ AMa,
    const short* __restrict__ Qc, const short* __restrict__ Kc,
    const short* __restrict__ Vtc, short* __restrict__ AMc) {
  const int t = threadIdx.x, wid = t >> 6, lane = t & 63;
  const int l32 = lane & 31, half = lane >> 5;
  const int bh = blockIdx.y;
  const int qbase = blockIdx.x * 32;
  const int inst = blockIdx.z;
  const short* Q = inst ? Qc : Qa;
  const short* K = inst ? Kc : Ka;
  const short* Vt = inst ? Vtc : Vta;
  short* AM = inst ? AMc : AMa;
  const size_t headoff = (size_t)bh * SS;
  const bool hi = (half == 1);

  __shared__ float pnum[4][32 * 16];  // [wave][q*16+d]
  __shared__ float pl[4][32];         // [wave][q]

  // Q B-frag (32x32x16): n=q=l32, k=half*8+j (pre-scaled by 0.25*log2e)
  const frag8 qf = *(const frag8*)&Q[(headoff + qbase + l32) * HDIM + half * 8];

  floatx16 acc = {0.f};  // C[q(reg)][n=l32]: n<16 -> O'[q][d], n==16 -> l[q]

  const int keyw = wid * 512;
#pragma unroll 1
  for (int it = 0; it < 16; it++) {
    const int kb = keyw + it * 32;
    // K A-frag: m=key=l32, k=half*8+j
    const frag8 kf = *(const frag8*)&K[(headoff + kb + l32) * HDIM + half * 8];
    const floatx16 z16 = {0.f};
    // C[m=key][n=q]: lane=q, reg r -> key = (r&3)+8*(r>>2)+4*half
    const floatx16 sc = __builtin_amdgcn_mfma_f32_32x32x16_bf16(kf, qf, z16, 0, 0, 0);
    // exp2 + pack pairs: u[2g+t] = keys 8g+4*half+2t+{0,1}
    unsigned ua[8];
#pragma unroll
    for (int p = 0; p < 8; p++) {
      ua[p] = pkbf(__builtin_amdgcn_exp2f(sc[2 * p]),
                   __builtin_amdgcn_exp2f(sc[2 * p + 1]));
    }
    // PV over two 16-key chunks; A-frag needs keys 16c+8*half+{0..7}:
    // own half supplies half of them, partner lane (lane^32) the other half.
#pragma unroll
    for (int c = 0; c < 2; c++) {
      const unsigned s0 = hi ? ua[4 * c + 0] : ua[4 * c + 2];  // what partner needs
      const unsigned s1 = hi ? ua[4 * c + 1] : ua[4 * c + 3];
      const unsigned y0 = __shfl_xor(s0, 32);
      const unsigned y1 = __shfl_xor(s1, 32);
      union { frag8 f; unsigned u[4]; } af;
      af.u[0] = hi ? y0 : ua[4 * c + 0];
      af.u[1] = hi ? y1 : ua[4 * c + 1];
      af.u[2] = hi ? ua[4 * c + 2] : y0;
      af.u[3] = hi ? ua[4 * c + 3] : y1;
      // Vt B-frag: n=l32 (row; 16=ones), k=half*8+j within the chunk
      const frag8 vf = *(const frag8*)&Vt[((size_t)bh * 32 + l32) * SS + kb + c * 16 + half * 8];
      acc = __builtin_amdgcn_mfma_f32_32x32x16_bf16(af.f, vf, acc, 0, 0, 0);
    }
  }

  // stage per-wave partials: lane (n=l32), reg r -> q=(r&3)+8*(r>>2)+4*half
  if (l32 < 16) {
#pragma unroll
    for (int r = 0; r < 16; r++) {
      const int q = (r & 3) + 8 * (r >> 2) + 4 * half;
      pnum[wid][q * 16 + l32] = acc[r];
    }
  } else if (l32 == 16) {
#pragma unroll
    for (int r = 0; r < 16; r++) {
      const int q = (r & 3) + 8 * (r >> 2) + 4 * half;
      pl[wid][q] = acc[r];
    }
  }
  __syncthreads();

  {
    const int b = bh >> 3, h = bh & 7;
#pragma unroll
    for (int idx = t; idx < 512; idx += 256) {
      const int d = idx & 15, q = idx >> 4;
      float num = 0.f, l = 0.f;
#pragma unroll
      for (int w = 0; w < 4; w++) {
        num += pnum[w][q * 16 + d];
        l += pl[w][q];
      }
      AM[((size_t)b * SS + qbase + q) * DD + d * 8 + h] = f2bf(num / l);
    }
  }
}

// ---------------- fused tail: residual GEMMs + norm + FFN (8-wave blocks) ----
// out = relu(LN@W3+b3)@W4 + b4 + R2, where R2 = AMs@w1 + AMc@w2 + b1+b2 + x_tgt
// and LN = (R2-mean)/var. R2/LN never hit global; FFN2 residual = in-register v.
__global__ __launch_bounds__(512) void tail_kernel(
    const short* __restrict__ AMs, const short* __restrict__ AMc,
    const short* __restrict__ W1, const short* __restrict__ W2,
    const float* __restrict__ b1, const float* __restrict__ b2,
    const float* __restrict__ x_tgt,
    const short* __restrict__ W3, const float* __restrict__ b3,
    const short* __restrict__ W4, const float* __restrict__ b4,
    float* __restrict__ Out) {
  const int t = threadIdx.x, w = t >> 6, lane = t & 63;
  const int quad = lane >> 4, l16 = lane & 15;
  const int mbase = blockIdx.x * 16;
  const int nA = w * 16 + l16;  // this wave's column in phases A and C

  __shared__ float sumS[8][16];
  __shared__ float sumQ[8][16];
  __shared__ short sLN[16 * LNS];
  __shared__ short hs[16 * HS];

  // ---- phase A: R2 col-slice = AMs@W1 + AMc@W2 + b1 + b2 + x_tgt ----
  floatx4 acc2 = (floatx4){0.f, 0.f, 0.f, 0.f};
#pragma unroll
  for (int ks = 0; ks < 4; ks++) {
    const frag8 afS = *(const frag8*)&AMs[(size_t)(mbase + l16) * DD + ks * 32 + quad * 8];
    const frag8 afC = *(const frag8*)&AMc[(size_t)(mbase + l16) * DD + ks * 32 + quad * 8];
    const frag8 bf1 = *(const frag8*)&W1[nA * DD + ks * 32 + quad * 8];
    const frag8 bf2 = *(const frag8*)&W2[nA * DD + ks * 32 + quad * 8];
    acc2 = __builtin_amdgcn_mfma_f32_16x16x32_bf16(afS, bf1, acc2, 0, 0, 0);
    acc2 = __builtin_amdgcn_mfma_f32_16x16x32_bf16(afC, bf2, acc2, 0, 0, 0);
  }

  float v[4];  // R2 values; survive to phase C as the residual
  {
    const float bn = b1[nA] + b2[nA];
#pragma unroll
    for (int r = 0; r < 4; r++) {
      const int m = mbase + quad * 4 + r;
      v[r] = acc2[r] + bn + x_tgt[(size_t)m * DD + nA];
    }
  }

  // ---- norm: per-wave 16-col partial sums, combined across 8 waves ----
#pragma unroll
  for (int r = 0; r < 4; r++) {
    float s = v[r];
    float sq = v[r] * v[r];
#pragma unroll
    for (int mk = 1; mk < 16; mk <<= 1) {
      s += __shfl_xor(s, mk, 64);
      sq += __shfl_xor(sq, mk, 64);
    }
    if (l16 == 0) {
      sumS[w][quad * 4 + r] = s;
      sumQ[w][quad * 4 + r] = sq;
    }
  }
  __syncthreads();

#pragma unroll
  for (int r = 0; r < 4; r++) {
    const int row = quad * 4 + r;
    float S = 0.f, Qs_ = 0.f;
#pragma unroll
    for (int ww = 0; ww < 8; ww++) { S += sumS[ww][row]; Qs_ += sumQ[ww][row]; }
    const float mean = S * (1.0f / 128.0f);
    const float cs = Qs_ - S * mean;        // sum of squared deviations
    const float ivar = 127.0f / cs;         // 1/var, var = cs/127 (faithful quirk)
    sLN[row * LNS + nA] = f2bf((v[r] - mean) * ivar);
  }
  __syncthreads();

  // ---- phase B: h = relu(LN @ W3 + b3), wave w -> h cols [w*64,(w+1)*64) ----
  {
    floatx4 acc[4];
#pragma unroll
    for (int ci = 0; ci < 4; ci++) acc[ci] = (floatx4){0.f, 0.f, 0.f, 0.f};
    const int nblk = w * 64;
#pragma unroll
    for (int ks = 0; ks < 4; ks++) {
      const frag8 af = *(const frag8*)&sLN[l16 * LNS + ks * 32 + quad * 8];
#pragma unroll
      for (int ci = 0; ci < 4; ci++) {
        const frag8 bf = *(const frag8*)&W3[(size_t)(nblk + ci * 16 + l16) * DD + ks * 32 + quad * 8];
        acc[ci] = __builtin_amdgcn_mfma_f32_16x16x32_bf16(af, bf, acc[ci], 0, 0, 0);
      }
    }
#pragma unroll
    for (int ci = 0; ci < 4; ci++) {
      const int n = nblk + ci * 16 + l16;
      const float bn = b3[n];
#pragma unroll
      for (int r = 0; r < 4; r++) {
        hs[(quad * 4 + r) * HS + n] = f2bf(fmaxf(acc[ci][r] + bn, 0.f));
      }
    }
  }
  __syncthreads();

  // ---- phase C: out = h @ W4 + b4 + v (in-register residual) ----
  {
    floatx4 acc = (floatx4){0.f, 0.f, 0.f, 0.f};
#pragma unroll 4
    for (int ks = 0; ks < 16; ks++) {
      const frag8 af = *(const frag8*)&hs[l16 * HS + ks * 32 + quad * 8];
      const frag8 bf = *(const frag8*)&W4[(size_t)nA * DF + ks * 32 + quad * 8];
      acc = __builtin_amdgcn_mfma_f32_16x16x32_bf16(af, bf, acc, 0, 0, 0);
    }
    const float bn = b4[nA];
#pragma unroll
    for (int r = 0; r < 4; r++) {
      const int m = mbase + quad * 4 + r;
      Out[(size_t)m * DD + nA] = acc[r] + bn + v[r];
    }
  }
}

extern "C" void kernel_launch(void* const* d_in, const int* in_sizes, int n_in,
                              void* d_out, int out_size, void* d_ws, size_t ws_size,
                              hipStream_t stream) {
  (void)in_sizes; (void)n_in; (void)out_size; (void)ws_size;
  const float* x_tgt   = (const float*)d_in[0];
  const float* enc_out = (const float*)d_in[1];
  const float* b1 = (const float*)d_in[9];
  const float* b2 = (const float*)d_in[11];
  const float* b3 = (const float*)d_in[13];
  const float* b4 = (const float*)d_in[15];

  WSrc wsrc;
  wsrc.p[0] = (const float*)d_in[2];   // self_wq
  wsrc.p[1] = (const float*)d_in[3];   // self_wk
  wsrc.p[2] = (const float*)d_in[4];   // self_wv
  wsrc.p[3] = (const float*)d_in[5];   // cross_wq
  wsrc.p[4] = (const float*)d_in[6];   // cross_wk
  wsrc.p[5] = (const float*)d_in[7];   // cross_wv
  wsrc.p[6] = (const float*)d_in[8];   // w1
  wsrc.p[7] = (const float*)d_in[10];  // w2
  wsrc.p[8] = (const float*)d_in[12];  // w3
  wsrc.p[9] = (const float*)d_in[14];  // w4

  // workspace layout (float-slot offsets; bf16 buffers use 2 elems per slot).
  // Vt buffers are 32 rows/head: (B,H,32,S) = 1,048,576 bf16 each.
  float* ws = (float*)d_ws;
  short* wt   = (short*)(ws + 0);          // 262144 bf16 (512 KB)
  short* Qs   = (short*)(ws + 131072);     // 524288 bf16
  short* Ks   = (short*)(ws + 393216);
  short* Vts  = (short*)(ws + 655360);     // 1048576 bf16 (32 rows/head)
  short* AMs  = (short*)(ws + 1179648);
  short* Qc   = (short*)(ws + 1441792);
  short* Kc   = (short*)(ws + 1703936);
  short* Vtc  = (short*)(ws + 1966080);    // 1048576 bf16
  short* AMc  = (short*)(ws + 2490368);

  const int M = BB * SS;  // 4096
  const int MT = M / 16;  // 256 row-tiles

  // slabs 0..9 = weight transpose/cvt; slab 10 = ones-row of Vt buffers
  wprep_kernel<<<dim3(64, 11), 256, 0, stream>>>(wsrc, wt, Vts, Vtc);

  // all 6 projections in one launch (cross-Q reads enc_out — faithful quirk)
  qkv_kernel<<<dim3(MT, 6), 128, 0, stream>>>(x_tgt, enc_out, wt, Qs, Ks, Vts, Qc, Kc, Vtc);

  // both attentions in one launch; LDS-free hot loop, split-K 4-wave blocks
  attn_mfma_kernel<<<dim3(SS / 32, BB * HH, 2), 256, 0, stream>>>(
      Qs, Ks, Vts, AMs, Qc, Kc, Vtc, AMc);

  // fused tail: residual GEMMs + norm + FFN (R2/LN never hit global)
  tail_kernel<<<MT, 512, 0, stream>>>(AMs, AMc, wt + 98304, wt + 114688,
                                      b1, b2, x_tgt, wt + 131072, b3,
                                      wt + 196608, b4, (float*)d_out);
}

// Round 13
// 143.403 us; speedup vs baseline: 1.0941x; 1.0843x over previous
//
#include <hip/hip_runtime.h>
#include <hip/hip_bf16.h>

// Problem constants
#define BB 2
#define SS 2048
#define DD 128
#define HH 8
#define HDIM 16
#define DF 512
#define SPK 36        // attn P stride (shorts); 72B rows
#define HS 520        // ffn LDS h stride (shorts; %8==0 for b128 alignment)
#define LNS 136       // LN LDS stride (shorts; %8==0 for b128 alignment)

typedef float floatx4 __attribute__((ext_vector_type(4)));
typedef float floatx16 __attribute__((ext_vector_type(16)));
typedef short frag8 __attribute__((ext_vector_type(8)));

__device__ __forceinline__ short f2bf(float x) {
  union { __hip_bfloat16 h; short s; } u;
  u.h = __float2bfloat16(x);
  return u.s;
}
// packed pair convert: v_cvt_pk_bf16_f32
__device__ __forceinline__ unsigned int pkbf(float a, float b) {
  float2 f; f.x = a; f.y = b;
  union { __hip_bfloat162 h2; unsigned int u; } u;
  u.h2 = __float22bfloat162_rn(f);
  return u.u;
}
__device__ __forceinline__ frag8 cvt8(const float4 a, const float4 b) {
  union { frag8 f; unsigned int u[4]; } x;
  x.u[0] = pkbf(a.x, a.y);
  x.u[1] = pkbf(a.z, a.w);
  x.u[2] = pkbf(b.x, b.y);
  x.u[3] = pkbf(b.z, b.w);
  return x.f;
}

// ---------------- weight prep: WT[n][k] bf16, scale folded ----------------
struct WSrc { const float* p[10]; };
// order: self_wq,self_wk,self_wv,cross_wq,cross_wk,cross_wv,w1,w2,w3,w4
__global__ __launch_bounds__(256) void wprep_kernel(WSrc w, short* __restrict__ dst) {
  const int wi = blockIdx.y;
  const int kshift = (wi == 9) ? 9 : 7;          // K: 512 for w4, else 128
  const int N = (wi == 8) ? 512 : 128;           // w3 has N=512
  const int total = N << kshift;
  const int offs[10] = {0, 16384, 32768, 49152, 65536, 81920, 98304, 114688, 131072, 196608};
  // fold 1/sqrt(HD) AND log2(e) into Wq: scores land in log2 domain -> bare v_exp
  const float sc = (wi == 0 || wi == 3) ? 0.25f * 1.4426950408889634f : 1.0f;
  const float* src = w.p[wi];
  short* d = dst + offs[wi];
  const int K = 1 << kshift;
  for (int idx = blockIdx.x * 256 + threadIdx.x; idx < total; idx += gridDim.x * 256) {
    const int n = idx >> kshift, k = idx & (K - 1);
    d[idx] = f2bf(src[k * N + n] * sc);
  }
}

// ---------------- fused 6-way QKV projection (MFMA) ----------------
// grid (M/16, 6), block 64. blockIdx.y: 0..2 self QKV (A=x_tgt),
// 3 cross Q (A=enc_out, quirk), 4..5 cross K/V (A=x_tgt).
__global__ __launch_bounds__(64) void qkv_kernel(const float* __restrict__ x_tgt,
                                                 const float* __restrict__ enc_out,
                                                 const short* __restrict__ wt,
                                                 short* __restrict__ Qs, short* __restrict__ Ks,
                                                 short* __restrict__ Vts,
                                                 short* __restrict__ Qc, short* __restrict__ Kc,
                                                 short* __restrict__ Vtc) {
  const int lane = threadIdx.x, quad = lane >> 4, l16 = lane & 15;
  const int mbase = blockIdx.x * 16;
  const int which = blockIdx.y;
  const int kind = which % 3;  // 0=Q,1=K,2=Vt
  const float* A = (which == 3) ? enc_out : x_tgt;
  const short* W = wt + which * 16384;
  short* Qb = (which < 3) ? Qs : Qc;
  short* Kb = (which < 3) ? Ks : Kc;
  short* Vtb = (which < 3) ? Vts : Vtc;

  __shared__ short sC[16 * 130];  // [m-local][n] bf16, stride 130

  floatx4 acc[8];
#pragma unroll
  for (int ct = 0; ct < 8; ct++) acc[ct] = (floatx4){0.f, 0.f, 0.f, 0.f};

#pragma unroll
  for (int ks = 0; ks < 4; ks++) {
    const float4* ar = (const float4*)&A[(size_t)(mbase + l16) * DD + ks * 32 + quad * 8];
    const frag8 af = cvt8(ar[0], ar[1]);
#pragma unroll
    for (int ct = 0; ct < 8; ct++) {
      const frag8 bf = *(const frag8*)&W[(ct * 16 + l16) * DD + ks * 32 + quad * 8];
      acc[ct] = __builtin_amdgcn_mfma_f32_16x16x32_bf16(af, bf, acc[ct], 0, 0, 0);
    }
  }

#pragma unroll
  for (int ct = 0; ct < 8; ct++) {
#pragma unroll
    for (int r = 0; r < 4; r++) {
      sC[(quad * 4 + r) * 130 + ct * 16 + l16] = f2bf(acc[ct][r]);
    }
  }
  // single wave per block: compiler's lgkmcnt ordering suffices (no barrier)

  const int b = mbase >> 11;
  const int sbase = mbase & 2047;
  if (kind <= 1) {
    short* Dst = (kind == 0) ? Qb : Kb;
    const int s = lane >> 2, c4 = lane & 3;
#pragma unroll
    for (int h = 0; h < 8; h++) {
      short4 v;  // split quirk: n = dci*8 + h
      v.x = sC[s * 130 + (c4 * 4 + 0) * 8 + h];
      v.y = sC[s * 130 + (c4 * 4 + 1) * 8 + h];
      v.z = sC[s * 130 + (c4 * 4 + 2) * 8 + h];
      v.w = sC[s * 130 + (c4 * 4 + 3) * 8 + h];
      const int bh = b * HH + h;
      *(short4*)&Dst[((size_t)bh * SS + sbase + s) * HDIM + c4 * 4] = v;
    }
  } else {
    const int dci = lane >> 2, c4 = lane & 3;
#pragma unroll
    for (int h = 0; h < 8; h++) {
      short4 v;
      v.x = sC[(c4 * 4 + 0) * 130 + dci * 8 + h];
      v.y = sC[(c4 * 4 + 1) * 130 + dci * 8 + h];
      v.z = sC[(c4 * 4 + 2) * 130 + dci * 8 + h];
      v.w = sC[(c4 * 4 + 3) * 130 + dci * 8 + h];
      const int bh = b * HH + h;
      *(short4*)&Vtb[((size_t)bh * HDIM + dci) * SS + sbase + c4 * 4] = v;
    }
  }
}

// ---------------- MFMA flash attention: 32x32x16 QK, split-K 4-wave blocks ----
// grid (SS/32, BB*HH, 2), block 256 = 4 waves; wave w owns keys [w*512, w*512+512).
// Q pre-scaled by 1/sqrt(HD)*log2(e): numerators via bare v_exp_f32.
// SOFTWARE PIPELINE: next iteration's kf/vf global loads are issued at the top
// of the body, so their ~200-cyc L2 latency is hidden under the exp phase.
__global__ __launch_bounds__(256) void attn_mfma_kernel(
    const short* __restrict__ Qa, const short* __restrict__ Ka,
    const short* __restrict__ Vta, short* __restrict__ AMa,
    const short* __restrict__ Qc, const short* __restrict__ Kc,
    const short* __restrict__ Vtc, short* __restrict__ AMc) {
  const int t = threadIdx.x, wid = t >> 6, lane = t & 63;
  const int l32 = lane & 31, half = lane >> 5;   // 32-wide frag coords
  const int quad = (lane >> 4) & 3, l16 = lane & 15;
  const int bh = blockIdx.y;
  const int qbase = blockIdx.x * 32;
  const int inst = blockIdx.z;
  const short* Q = inst ? Qc : Qa;
  const short* K = inst ? Kc : Ka;
  const short* Vt = inst ? Vtc : Vta;
  short* AM = inst ? AMc : AMa;
  const size_t headoff = (size_t)bh * SS;

  __shared__ short sP[4][32 * SPK];   // [wave][q][key(32)] bf16
  __shared__ float pnum[4][16 * 33];  // [wave][d*33+q]
  __shared__ float pl[4][32];

  // Q B-frag (32x32x16): n=q=l32, k=half*8+j
  const frag8 qf = *(const frag8*)&Q[(headoff + qbase + l32) * HDIM + half * 8];

  frag8 onef;
#pragma unroll
  for (int i = 0; i < 8; i++) onef[i] = (short)0x3f80;  // bf16 1.0

  floatx4 acc_o[2], acc_l[2];
  acc_o[0] = (floatx4){0.f, 0.f, 0.f, 0.f}; acc_o[1] = acc_o[0];
  acc_l[0] = acc_o[0]; acc_l[1] = acc_o[0];

  const int keyw = wid * 512;
  const short* Kp = K + (headoff + l32) * HDIM + half * 8;   // + key*HDIM
  const short* Vp = Vt + ((size_t)bh * HDIM + l16) * SS + quad * 8;  // + kb

  // pipeline prologue: operands for it=0
  frag8 kf = *(const frag8*)&Kp[(size_t)keyw * HDIM];
  frag8 vf = *(const frag8*)&Vp[keyw];

#pragma unroll 1
  for (int it = 0; it < 16; it++) {
    const int kb = keyw + it * 32;
    const int nb = keyw + ((it + 1 < 16) ? (it + 1) : 15) * 32;  // clamped prefetch
    // prefetch next iteration's operands (latency hidden under exp phase)
    const frag8 kf_n = *(const frag8*)&Kp[(size_t)nb * HDIM];
    const frag8 vf_n = *(const frag8*)&Vp[nb];

    const floatx16 z16 = {0.f};
    // C[m=key][n=q]: lane=q, reg r -> key = (r&3)+8*(r>>2)+4*half
    const floatx16 sc = __builtin_amdgcn_mfma_f32_32x32x16_bf16(kf, qf, z16, 0, 0, 0);
    // bare v_exp + packed cvt: reg group g = keys 8g+4*half+0..3 at fixed q=l32
#pragma unroll
    for (int g = 0; g < 4; g++) {
      const float e0 = __builtin_amdgcn_exp2f(sc[4 * g + 0]);
      const float e1 = __builtin_amdgcn_exp2f(sc[4 * g + 1]);
      const float e2 = __builtin_amdgcn_exp2f(sc[4 * g + 2]);
      const float e3 = __builtin_amdgcn_exp2f(sc[4 * g + 3]);
      uint2 pk;
      pk.x = pkbf(e0, e1);
      pk.y = pkbf(e2, e3);
      *(uint2*)&sP[wid][l32 * SPK + g * 8 + half * 4] = pk;
    }
    // PV (operand-swapped, 16x16x32): C[d][q'] += Vt(16d x 32k) @ P^T(32k x 16q')
#pragma unroll
    for (int qh = 0; qh < 2; qh++) {
      const frag8 pf = *(const frag8*)&sP[wid][(qh * 16 + l16) * SPK + quad * 8];
      acc_o[qh] = __builtin_amdgcn_mfma_f32_16x16x32_bf16(vf, pf, acc_o[qh], 0, 0, 0);
      acc_l[qh] = __builtin_amdgcn_mfma_f32_16x16x32_bf16(onef, pf, acc_l[qh], 0, 0, 0);
    }
    kf = kf_n;
    vf = vf_n;
  }

  // stage per-wave partials: acc_o[qh] reg r = num[d=quad*4+r][q=qh*16+l16]
  {
    float* pn = &pnum[wid][0];
    float* plw = &pl[wid][0];
#pragma unroll
    for (int qh = 0; qh < 2; qh++) {
#pragma unroll
      for (int r = 0; r < 4; r++) {
        pn[(quad * 4 + r) * 33 + qh * 16 + l16] = acc_o[qh][r];
      }
      if (quad == 0) plw[qh * 16 + l16] = acc_l[qh][0];  // rows replicated
    }
  }
  __syncthreads();

  {
    const int b = bh >> 3, h = bh & 7;
#pragma unroll
    for (int idx = t; idx < 512; idx += 256) {
      const int q16 = idx & 31, d = idx >> 5;
      float num = 0.f, l = 0.f;
#pragma unroll
      for (int w = 0; w < 4; w++) {
        num += pnum[w][d * 33 + q16];
        l += pl[w][q16];
      }
      AM[((size_t)b * SS + qbase + q16) * DD + d * 8 + h] = f2bf(num / l);
    }
  }
}

// ---------------- fused tail: residual GEMMs + norm + FFN ----------------
// out = relu(LN@W3+b3)@W4 + b4 + R2, where R2 = AMs@w1 + AMc@w2 + b1+b2 + x_tgt
// and LN = (R2-mean)/var. R2/LN never hit global; FFN2 residual = in-register v.
// grid M/16, block 256 = 4 waves; wave w owns out cols [w*32, w*32+32).
__global__ __launch_bounds__(256) void tail_kernel(
    const short* __restrict__ AMs, const short* __restrict__ AMc,
    const short* __restrict__ W1, const short* __restrict__ W2,
    const float* __restrict__ b1, const float* __restrict__ b2,
    const float* __restrict__ x_tgt,
    const short* __restrict__ W3, const float* __restrict__ b3,
    const short* __restrict__ W4, const float* __restrict__ b4,
    float* __restrict__ Out) {
  const int t = threadIdx.x, w = t >> 6, lane = t & 63;
  const int quad = lane >> 4, l16 = lane & 15;
  const int mbase = blockIdx.x * 16;

  __shared__ float sumS[4][16];
  __shared__ float sumQ[4][16];
  __shared__ short sLN[16 * LNS];
  __shared__ short hs[16 * HS];

  // ---- phase A: R2 tile = AMs@W1 + AMc@W2 + b1 + b2 + x_tgt ----
  floatx4 acc2[2];
  acc2[0] = (floatx4){0.f, 0.f, 0.f, 0.f};
  acc2[1] = (floatx4){0.f, 0.f, 0.f, 0.f};
#pragma unroll
  for (int ks = 0; ks < 4; ks++) {
    const frag8 afS = *(const frag8*)&AMs[(size_t)(mbase + l16) * DD + ks * 32 + quad * 8];
    const frag8 afC = *(const frag8*)&AMc[(size_t)(mbase + l16) * DD + ks * 32 + quad * 8];
#pragma unroll
    for (int c = 0; c < 2; c++) {
      const int n0 = (w * 2 + c) * 16 + l16;
      const frag8 bf1 = *(const frag8*)&W1[n0 * DD + ks * 32 + quad * 8];
      const frag8 bf2 = *(const frag8*)&W2[n0 * DD + ks * 32 + quad * 8];
      acc2[c] = __builtin_amdgcn_mfma_f32_16x16x32_bf16(afS, bf1, acc2[c], 0, 0, 0);
      acc2[c] = __builtin_amdgcn_mfma_f32_16x16x32_bf16(afC, bf2, acc2[c], 0, 0, 0);
    }
  }

  float v[2][4];  // R2 values; survive to phase C as the residual
#pragma unroll
  for (int c = 0; c < 2; c++) {
    const int n = w * 32 + c * 16 + l16;
    const float bn = b1[n] + b2[n];
#pragma unroll
    for (int r = 0; r < 4; r++) {
      const int m = mbase + quad * 4 + r;
      v[c][r] = acc2[c][r] + bn + x_tgt[(size_t)m * DD + n];
    }
  }

  // ---- norm: cross-wave row sums ----
#pragma unroll
  for (int r = 0; r < 4; r++) {
    float s = v[0][r] + v[1][r];
    float sq = v[0][r] * v[0][r] + v[1][r] * v[1][r];
#pragma unroll
    for (int mk = 1; mk < 16; mk <<= 1) {
      s += __shfl_xor(s, mk, 64);
      sq += __shfl_xor(sq, mk, 64);
    }
    if (l16 == 0) {
      sumS[w][quad * 4 + r] = s;
      sumQ[w][quad * 4 + r] = sq;
    }
  }
  __syncthreads();

#pragma unroll
  for (int r = 0; r < 4; r++) {
    const int row = quad * 4 + r;
    const float S = sumS[0][row] + sumS[1][row] + sumS[2][row] + sumS[3][row];
    const float Qs_ = sumQ[0][row] + sumQ[1][row] + sumQ[2][row] + sumQ[3][row];
    const float mean = S * (1.0f / 128.0f);
    const float cs = Qs_ - S * mean;        // sum of squared deviations
    const float ivar = 127.0f / cs;         // 1/var, var = cs/127 (faithful quirk)
#pragma unroll
    for (int c = 0; c < 2; c++) {
      const int n = w * 32 + c * 16 + l16;
      sLN[row * LNS + n] = f2bf((v[c][r] - mean) * ivar);
    }
  }
  __syncthreads();

  // ---- phase B: h = relu(LN @ W3 + b3), wave w -> h cols [w*128,(w+1)*128) ----
  {
    floatx4 acc[8];
#pragma unroll
    for (int ct = 0; ct < 8; ct++) acc[ct] = (floatx4){0.f, 0.f, 0.f, 0.f};
    const int nblk = w * 128;
#pragma unroll
    for (int ks = 0; ks < 4; ks++) {
      const frag8 af = *(const frag8*)&sLN[l16 * LNS + ks * 32 + quad * 8];
#pragma unroll
      for (int ct = 0; ct < 8; ct++) {
        const frag8 bf = *(const frag8*)&W3[(size_t)(nblk + ct * 16 + l16) * DD + ks * 32 + quad * 8];
        acc[ct] = __builtin_amdgcn_mfma_f32_16x16x32_bf16(af, bf, acc[ct], 0, 0, 0);
      }
    }
#pragma unroll
    for (int ct = 0; ct < 8; ct++) {
      const int n = nblk + ct * 16 + l16;
      const float bn = b3[n];
#pragma unroll
      for (int r = 0; r < 4; r++) {
        hs[(quad * 4 + r) * HS + n] = f2bf(fmaxf(acc[ct][r] + bn, 0.f));
      }
    }
  }
  __syncthreads();

  // ---- phase C: out = h @ W4 + b4 + v (in-register residual) ----
  {
    floatx4 acc[2];
    acc[0] = (floatx4){0.f, 0.f, 0.f, 0.f};
    acc[1] = (floatx4){0.f, 0.f, 0.f, 0.f};
#pragma unroll 4
    for (int ks = 0; ks < 16; ks++) {
      const frag8 af = *(const frag8*)&hs[l16 * HS + ks * 32 + quad * 8];
#pragma unroll
      for (int c = 0; c < 2; c++) {
        const int n0 = w * 32 + c * 16 + l16;
        const frag8 bf = *(const frag8*)&W4[(size_t)n0 * DF + ks * 32 + quad * 8];
        acc[c] = __builtin_amdgcn_mfma_f32_16x16x32_bf16(af, bf, acc[c], 0, 0, 0);
      }
    }
#pragma unroll
    for (int c = 0; c < 2; c++) {
      const int n = w * 32 + c * 16 + l16;
      const float bn = b4[n];
#pragma unroll
      for (int r = 0; r < 4; r++) {
        const int m = mbase + quad * 4 + r;
        Out[(size_t)m * DD + n] = acc[c][r] + bn + v[c][r];
      }
    }
  }
}

extern "C" void kernel_launch(void* const* d_in, const int* in_sizes, int n_in,
                              void* d_out, int out_size, void* d_ws, size_t ws_size,
                              hipStream_t stream) {
  (void)in_sizes; (void)n_in; (void)out_size; (void)ws_size;
  const float* x_tgt   = (const float*)d_in[0];
  const float* enc_out = (const float*)d_in[1];
  const float* b1 = (const float*)d_in[9];
  const float* b2 = (const float*)d_in[11];
  const float* b3 = (const float*)d_in[13];
  const float* b4 = (const float*)d_in[15];

  WSrc wsrc;
  wsrc.p[0] = (const float*)d_in[2];   // self_wq
  wsrc.p[1] = (const float*)d_in[3];   // self_wk
  wsrc.p[2] = (const float*)d_in[4];   // self_wv
  wsrc.p[3] = (const float*)d_in[5];   // cross_wq
  wsrc.p[4] = (const float*)d_in[6];   // cross_wk
  wsrc.p[5] = (const float*)d_in[7];   // cross_wv
  wsrc.p[6] = (const float*)d_in[8];   // w1
  wsrc.p[7] = (const float*)d_in[10];  // w2
  wsrc.p[8] = (const float*)d_in[12];  // w3
  wsrc.p[9] = (const float*)d_in[14];  // w4

  // workspace layout (float-slot offsets; bf16 buffers use 2 elems per slot)
  float* ws = (float*)d_ws;
  short* wt   = (short*)(ws + 0);          // 262144 bf16 (512 KB)
  short* Qs   = (short*)(ws + 131072);     // each QKV buf: 524288 bf16
  short* Ks   = (short*)(ws + 393216);
  short* Vts  = (short*)(ws + 655360);
  short* AMs  = (short*)(ws + 917504);
  short* Qc   = (short*)(ws + 1179648);
  short* Kc   = (short*)(ws + 1441792);
  short* Vtc  = (short*)(ws + 1703936);
  short* AMc  = (short*)(ws + 1966080);

  const int M = BB * SS;  // 4096
  const int MT = M / 16;  // 256 row-tiles

  wprep_kernel<<<dim3(64, 10), 256, 0, stream>>>(wsrc, wt);

  // all 6 projections in one launch (cross-Q reads enc_out — faithful quirk)
  qkv_kernel<<<dim3(MT, 6), 64, 0, stream>>>(x_tgt, enc_out, wt, Qs, Ks, Vts, Qc, Kc, Vtc);

  // both attentions in one launch; 32-query waves, split-K 4-wave blocks
  attn_mfma_kernel<<<dim3(SS / 32, BB * HH, 2), 256, 0, stream>>>(
      Qs, Ks, Vts, AMs, Qc, Kc, Vtc, AMc);

  // fused tail: residual GEMMs + norm + FFN (R2/LN never hit global)
  tail_kernel<<<MT, 256, 0, stream>>>(AMs, AMc, wt + 98304, wt + 114688,
                                      b1, b2, x_tgt, wt + 131072, b3,
                                      wt + 196608, b4, (float*)d_out);
}